// Round 8
// baseline (149.198 us; speedup 1.0000x reference)
//
#include <hip/hip_runtime.h>
#include <math.h>

constexpr int B = 1024;
constexpr int D = 128;
constexpr int Q = 65536;
constexpr int NPART = 1024;      // partial-sumexp slots per row (512 col-blocks x 2 wave-cols)
#define TEMP_INV 5.0f
#define EPS 1e-12f

typedef __bf16 bf16x8 __attribute__((ext_vector_type(8)));
typedef float  f32x4  __attribute__((ext_vector_type(4)));

__device__ __forceinline__ float wave_reduce_sum(float v) {
    #pragma unroll
    for (int off = 32; off > 0; off >>= 1) v += __shfl_xor(v, off);
    return v;
}

__device__ __forceinline__ unsigned short f2bf(float x) {
    unsigned int u = __float_as_uint(x);
    unsigned int r = (u + 0x7FFFu + ((u >> 16) & 1u)) >> 16;   // RNE
    return (unsigned short)r;
}

// --- K1: fused preprocessing ----------------------------------------------
// blocks [0, 8192):  l2-normalize 8 queue rows -> bf16 qb
// blocks [8192, 8704): normalize 2 g1/g2 rows -> qnb bf16, pos_sim
__global__ __launch_bounds__(256) void k_prep(const float* __restrict__ g1,
                                              const float* __restrict__ g2,
                                              const float* __restrict__ queue,
                                              unsigned short* __restrict__ qnb,
                                              unsigned short* __restrict__ qb,
                                              float* __restrict__ out_pos) {
    if (blockIdx.x < Q / 8) {
        int half = threadIdx.x >> 5;        // 0..7
        int l    = threadIdx.x & 31;
        int row  = blockIdx.x * 8 + half;
        const f32x4* src = (const f32x4*)(queue + (size_t)row * D);
        f32x4 v = __builtin_nontemporal_load(&src[l]);
        float ss = v.x * v.x + v.y * v.y + v.z * v.z + v.w * v.w;
        #pragma unroll
        for (int off = 16; off > 0; off >>= 1) ss += __shfl_xor(ss, off);
        float inv = 1.0f / fmaxf(sqrtf(ss), EPS);
        uint2 o;
        o.x = (unsigned int)f2bf(v.x * inv) | ((unsigned int)f2bf(v.y * inv) << 16);
        o.y = (unsigned int)f2bf(v.z * inv) | ((unsigned int)f2bf(v.w * inv) << 16);
        ((uint2*)(qb + (size_t)row * D))[l] = o;
    } else {
        int idx = blockIdx.x - Q / 8;
        int w2 = threadIdx.x >> 7;          // row within block (0..1)
        int tt = threadIdx.x & 127;         // 0..127 feature dim
        int b  = idx * 2 + w2;
        int w  = tt >> 6, lane = tt & 63;
        float x = g1[b * D + tt];
        float y = g2[b * D + tt];
        __shared__ float sx[2][2], sy[2][2], sp[2][2];
        float xs = wave_reduce_sum(x * x);
        float ys = wave_reduce_sum(y * y);
        if (lane == 0) { sx[w2][w] = xs; sy[w2][w] = ys; }
        __syncthreads();
        float ix = 1.0f / fmaxf(sqrtf(sx[w2][0] + sx[w2][1]), EPS);
        float iy = 1.0f / fmaxf(sqrtf(sy[w2][0] + sy[w2][1]), EPS);
        float qv = x * ix;
        float kv = y * iy;
        qnb[b * D + tt] = f2bf(qv);
        float p = wave_reduce_sum(qv * kv);
        if (lane == 0) sp[w2][w] = p;
        __syncthreads();
        if (tt == 0) {
            out_pos[b] = (sp[w2][0] + sp[w2][1]) * TEMP_INV;
        }
    }
}

// --- K2: MFMA GEMM + fused fixed-ref partial sumexp -----------------------
// C[b][j] = (qn[b].qb[j])*5 ; 128x128 tile, 4 waves (2x2), 64x64 per wave
// 1-D grid, by-fastest: 8 consecutive blocks share one qb tile -> L3 reuse
// Epilogue: per-wave private LDS transpose (no block barriers after K-loop)
__global__ __launch_bounds__(256, 3) void k_gemm_mfma(const unsigned short* __restrict__ qnb,
                                                      const unsigned short* __restrict__ qb,
                                                      float* __restrict__ neg,
                                                      float* __restrict__ psum) {
    __shared__ unsigned short As[128][72];   // +8 pad: 144B row stride
    __shared__ unsigned short Bs[128][72];
    const int t  = threadIdx.x;
    const int blk = blockIdx.x;
    const int bx = blk >> 3;       // 0..511 over Q (slow)
    const int by = blk & 7;        // 0..7   over B (fast -> qb-tile reuse)
    const int R0 = by * 128, C0 = bx * 128;
    const int wid = t >> 6, lane = t & 63;
    const int wr = wid >> 1, wc = wid & 1;
    const int lg = lane >> 4, lc = lane & 15;

    f32x4 acc[4][4];
    #pragma unroll
    for (int m = 0; m < 4; ++m)
        #pragma unroll
        for (int n = 0; n < 4; ++n)
            #pragma unroll
            for (int r = 0; r < 4; ++r) acc[m][n][r] = 0.0f;

    #pragma unroll
    for (int s = 0; s < 2; ++s) {
        if (s) __syncthreads();
        const int ks = s * 64;
        #pragma unroll
        for (int p = 0; p < 4; ++p) {
            int c   = t + 256 * p;
            int row = c >> 3;          // 0..127
            int off = (c & 7) * 8;     // bf16 units, 0..56
            uint4 va = *(const uint4*)(qnb + (size_t)(R0 + row) * D + ks + off);
            uint4 vb = *(const uint4*)(qb  + (size_t)(C0 + row) * D + ks + off);
            *(uint4*)&As[row][off] = va;
            *(uint4*)&Bs[row][off] = vb;
        }
        __syncthreads();
        #pragma unroll
        for (int kk = 0; kk < 64; kk += 32) {
            int ko = kk + lg * 8;
            bf16x8 a[4], b[4];
            #pragma unroll
            for (int m = 0; m < 4; ++m)
                a[m] = *(const bf16x8*)&As[wr * 64 + m * 16 + lc][ko];
            #pragma unroll
            for (int n = 0; n < 4; ++n)
                b[n] = *(const bf16x8*)&Bs[wc * 64 + n * 16 + lc][ko];
            #pragma unroll
            for (int m = 0; m < 4; ++m)
                #pragma unroll
                for (int n = 0; n < 4; ++n)
                    acc[m][n] = __builtin_amdgcn_mfma_f32_16x16x32_bf16(a[m], b[n], acc[m][n], 0, 0, 0);
        }
    }

    // ---- epilogue: ONE barrier (retire MFMA LDS reads), then each wave
    //      independently transposes its 64x64 tile in 16-row slices through
    //      a private [16][65] f32 scratch (aliased over As), and streams
    //      coalesced float4 stores. Fixed LSE reference M=5 (logits in [-5,5]).
    __syncthreads();
    float* Ws = (float*)&As[0][0] + wid * (16 * 65);   // 4x4160B = 16640 <= 18432
    const int slot = bx * 2 + wc;
    const int rrow = lane >> 2;        // 0..15 (store-side row)
    const int cc   = lane & 3;         // 0..3  (store-side 16-f32 chunk)
    #pragma unroll
    for (int m = 0; m < 4; ++m) {
        #pragma unroll
        for (int reg = 0; reg < 4; ++reg) {
            float v0 = acc[m][0][reg] * TEMP_INV;
            float v1 = acc[m][1][reg] * TEMP_INV;
            float v2 = acc[m][2][reg] * TEMP_INV;
            float v3 = acc[m][3][reg] * TEMP_INV;
            int wrow = lg * 4 + reg;
            Ws[wrow * 65 +  0 + lc] = v0;
            Ws[wrow * 65 + 16 + lc] = v1;
            Ws[wrow * 65 + 32 + lc] = v2;
            Ws[wrow * 65 + 48 + lc] = v3;
            float e = __expf(v0 - 5.0f) + __expf(v1 - 5.0f) +
                      __expf(v2 - 5.0f) + __expf(v3 - 5.0f);
            #pragma unroll
            for (int off = 1; off < 16; off <<= 1) e += __shfl_xor(e, off);
            if (lc == 0) {
                int gr = R0 + wr * 64 + m * 16 + wrow;
                psum[(size_t)gr * NPART + slot] = e;
            }
        }
        // wave-local read-back + store (in-wave DS ordering; no barrier)
        const float* src = Ws + rrow * 65 + cc * 16;
        int gr = R0 + wr * 64 + m * 16 + rrow;
        float* dst = neg + (size_t)gr * Q + C0 + wc * 64 + cc * 16;
        #pragma unroll
        for (int j = 0; j < 4; ++j) {
            float4 o = *(const float4*)(src + j * 4);
            *(float4*)(dst + j * 4) = o;
        }
    }
}

// --- K3: reduce 1024 partial sums per row + pos -> atomic mean loss -------
__global__ __launch_bounds__(256) void k_reduce_lse(const float* __restrict__ psum,
                                                    const float* __restrict__ out_pos,
                                                    float* __restrict__ out) {
    int r = blockIdx.x;
    const float4* pr = (const float4*)(psum + (size_t)r * NPART);
    float4 v = pr[threadIdx.x];        // 256 threads x float4 = 1024 slots
    float s = v.x + v.y + v.z + v.w;
    s = wave_reduce_sum(s);
    __shared__ float sw[4];
    int w = threadIdx.x >> 6, lane = threadIdx.x & 63;
    if (lane == 0) sw[w] = s;
    __syncthreads();
    if (threadIdx.x == 0) {
        float S = sw[0] + sw[1] + sw[2] + sw[3];
        float pos = out_pos[r];
        S += __expf(pos - 5.0f);
        float loss = (logf(S) + 5.0f) - pos;   // lse - pos
        atomicAdd(out, loss * (1.0f / (float)B));
    }
}

extern "C" void kernel_launch(void* const* d_in, const int* in_sizes, int n_in,
                              void* d_out, int out_size, void* d_ws, size_t ws_size,
                              hipStream_t stream) {
    const float* g1    = (const float*)d_in[0];
    const float* g2    = (const float*)d_in[1];
    const float* queue = (const float*)d_in[2];
    float* out = (float*)d_out;

    float* out_pos = out + 1;          // pos_sim [B]
    float* neg     = out + 1 + B;      // neg_sim [B][Q]

    // ws layout: qnb bf16[B*D] | qb bf16[Q*D] | psum f32[B*NPART]
    unsigned short* qnb = (unsigned short*)d_ws;
    unsigned short* qb  = qnb + (size_t)B * D;
    float* psum = (float*)(qb + (size_t)Q * D);

    hipMemsetAsync(out, 0, sizeof(float), stream);   // loss accumulator
    k_prep<<<Q / 8 + B / 2, 256, 0, stream>>>(g1, g2, queue, qnb, qb, out_pos);
    k_gemm_mfma<<<(Q / 128) * (B / 128), 256, 0, stream>>>(qnb, qb, neg, psum);
    k_reduce_lse<<<B, 256, 0, stream>>>(psum, out_pos, out);
}

// Round 9
// 107.821 us; speedup vs baseline: 1.3838x; 1.3838x over previous
//
#include <hip/hip_runtime.h>
#include <math.h>

constexpr int B = 1024;
constexpr int D = 128;
constexpr int Q = 65536;
constexpr int NPART = 1024;      // partial-sumexp slots per row (512 col-blocks x 2 wave-cols)
#define TEMP_INV 5.0f
#define EPS 1e-12f

typedef __bf16 bf16x8 __attribute__((ext_vector_type(8)));
typedef float  f32x4  __attribute__((ext_vector_type(4)));

__device__ __forceinline__ float wave_reduce_sum(float v) {
    #pragma unroll
    for (int off = 32; off > 0; off >>= 1) v += __shfl_xor(v, off);
    return v;
}

__device__ __forceinline__ unsigned short f2bf(float x) {
    unsigned int u = __float_as_uint(x);
    unsigned int r = (u + 0x7FFFu + ((u >> 16) & 1u)) >> 16;   // RNE
    return (unsigned short)r;
}

// --- K1: preprocessing -----------------------------------------------------
// blocks [0, 8192):  queue row inverse norms -> qinv (queue stays L3-hot)
// blocks [8192, 8704): normalize 2 g1/g2 rows -> qnb bf16, pos_sim
__global__ __launch_bounds__(256) void k_prep(const float* __restrict__ g1,
                                              const float* __restrict__ g2,
                                              const float* __restrict__ queue,
                                              unsigned short* __restrict__ qnb,
                                              float* __restrict__ qinv,
                                              float* __restrict__ out_pos,
                                              float* __restrict__ ws_pos) {
    if (blockIdx.x < Q / 8) {
        int half = threadIdx.x >> 5;        // 0..7
        int l    = threadIdx.x & 31;
        int row  = blockIdx.x * 8 + half;
        const f32x4* src = (const f32x4*)(queue + (size_t)row * D);
        f32x4 v = src[l];                   // cached load: keep queue in L3 for gemm
        float ss = v.x * v.x + v.y * v.y + v.z * v.z + v.w * v.w;
        #pragma unroll
        for (int off = 16; off > 0; off >>= 1) ss += __shfl_xor(ss, off);
        if (l == 0) qinv[row] = 1.0f / fmaxf(sqrtf(ss), EPS);
    } else {
        int idx = blockIdx.x - Q / 8;
        int w2 = threadIdx.x >> 7;          // row within block (0..1)
        int tt = threadIdx.x & 127;         // 0..127 feature dim
        int b  = idx * 2 + w2;
        int w  = tt >> 6, lane = tt & 63;
        float x = g1[b * D + tt];
        float y = g2[b * D + tt];
        __shared__ float sx[2][2], sy[2][2], sp[2][2];
        float xs = wave_reduce_sum(x * x);
        float ys = wave_reduce_sum(y * y);
        if (lane == 0) { sx[w2][w] = xs; sy[w2][w] = ys; }
        __syncthreads();
        float ix = 1.0f / fmaxf(sqrtf(sx[w2][0] + sx[w2][1]), EPS);
        float iy = 1.0f / fmaxf(sqrtf(sy[w2][0] + sy[w2][1]), EPS);
        float qv = x * ix;
        float kv = y * iy;
        qnb[b * D + tt] = f2bf(qv);
        float p = wave_reduce_sum(qv * kv);
        if (lane == 0) sp[w2][w] = p;
        __syncthreads();
        if (tt == 0) {
            float pos = (sp[w2][0] + sp[w2][1]) * TEMP_INV;
            out_pos[b] = pos;
            ws_pos[b]  = pos;
        }
    }
}

// --- K2: MFMA GEMM + fused fixed-ref partial sumexp -----------------------
// C[b][j] = (qn[b].qnorm[j])*5 ; 128x128 tile, 4 waves (2x2), 64x64 per wave
// B staged directly from fp32 queue (L3-resident), scaled by qinv, cvt bf16
// 1-D grid, by-fastest: 8 consecutive blocks share one queue tile -> L3 reuse
__global__ __launch_bounds__(256, 3) void k_gemm_mfma(const unsigned short* __restrict__ qnb,
                                                      const float* __restrict__ queue,
                                                      const float* __restrict__ qinv,
                                                      float* __restrict__ neg,
                                                      float* __restrict__ psum) {
    __shared__ unsigned short As[128][72];   // +8 pad: 144B row stride
    __shared__ unsigned short Bs[128][72];
    const int t  = threadIdx.x;
    const int blk = blockIdx.x;
    const int bx = blk >> 3;       // 0..511 over Q (slow)
    const int by = blk & 7;        // 0..7   over B (fast -> queue-tile reuse)
    const int R0 = by * 128, C0 = bx * 128;
    const int wid = t >> 6, lane = t & 63;
    const int wr = wid >> 1, wc = wid & 1;
    const int lg = lane >> 4, lc = lane & 15;

    f32x4 acc[4][4];
    #pragma unroll
    for (int m = 0; m < 4; ++m)
        #pragma unroll
        for (int n = 0; n < 4; ++n)
            #pragma unroll
            for (int r = 0; r < 4; ++r) acc[m][n][r] = 0.0f;

    #pragma unroll
    for (int s = 0; s < 2; ++s) {
        if (s) __syncthreads();
        const int ks = s * 64;
        #pragma unroll
        for (int p = 0; p < 4; ++p) {
            int c   = t + 256 * p;
            int row = c >> 3;          // 0..127
            int off = (c & 7) * 8;     // bf16/f32 col offset, 0..56
            // A: bf16 16B load
            uint4 va = *(const uint4*)(qnb + (size_t)(R0 + row) * D + ks + off);
            *(uint4*)&As[row][off] = va;
            // B: fp32 queue row segment * qinv -> bf16x8
            const float* qrow = queue + (size_t)(C0 + row) * D + ks + off;
            float inv = qinv[C0 + row];
            f32x4 u0 = *(const f32x4*)(qrow);
            f32x4 u1 = *(const f32x4*)(qrow + 4);
            uint4 vb;
            vb.x = (unsigned int)f2bf(u0.x * inv) | ((unsigned int)f2bf(u0.y * inv) << 16);
            vb.y = (unsigned int)f2bf(u0.z * inv) | ((unsigned int)f2bf(u0.w * inv) << 16);
            vb.z = (unsigned int)f2bf(u1.x * inv) | ((unsigned int)f2bf(u1.y * inv) << 16);
            vb.w = (unsigned int)f2bf(u1.z * inv) | ((unsigned int)f2bf(u1.w * inv) << 16);
            *(uint4*)&Bs[row][off] = vb;
        }
        __syncthreads();
        #pragma unroll
        for (int kk = 0; kk < 64; kk += 32) {
            int ko = kk + lg * 8;
            bf16x8 a[4], b[4];
            #pragma unroll
            for (int m = 0; m < 4; ++m)
                a[m] = *(const bf16x8*)&As[wr * 64 + m * 16 + lc][ko];
            #pragma unroll
            for (int n = 0; n < 4; ++n)
                b[n] = *(const bf16x8*)&Bs[wc * 64 + n * 16 + lc][ko];
            #pragma unroll
            for (int m = 0; m < 4; ++m)
                #pragma unroll
                for (int n = 0; n < 4; ++n)
                    acc[m][n] = __builtin_amdgcn_mfma_f32_16x16x32_bf16(a[m], b[n], acc[m][n], 0, 0, 0);
        }
    }

    // ---- epilogue: per 32-row slice: LDS transpose (reusing Bs), fused
    //      fixed-ref sumexp (logits in [-5,5] -> M=5), coalesced f4 stores
    float* Cs = (float*)&Bs[0][0];     // [32][132] f32 = 16896B <= sizeof(Bs)
    const int slot = bx * 2 + wc;
    #pragma unroll
    for (int m = 0; m < 4; ++m) {
        __syncthreads();               // prev slice's reads (or MFMA LDS reads) done
        #pragma unroll
        for (int reg = 0; reg < 4; ++reg) {
            float v0 = acc[m][0][reg] * TEMP_INV;
            float v1 = acc[m][1][reg] * TEMP_INV;
            float v2 = acc[m][2][reg] * TEMP_INV;
            float v3 = acc[m][3][reg] * TEMP_INV;
            int cr = (wr * 16 + lg * 4 + reg) * 132 + wc * 64 + lc;
            Cs[cr +  0] = v0;
            Cs[cr + 16] = v1;
            Cs[cr + 32] = v2;
            Cs[cr + 48] = v3;
            float e = __expf(v0 - 5.0f) + __expf(v1 - 5.0f) +
                      __expf(v2 - 5.0f) + __expf(v3 - 5.0f);
            #pragma unroll
            for (int off = 1; off < 16; off <<= 1) e += __shfl_xor(e, off);
            if (lc == 0) {
                int gr = R0 + wr * 64 + m * 16 + lg * 4 + reg;
                psum[(size_t)gr * NPART + slot] = e;
            }
        }
        __syncthreads();
        #pragma unroll
        for (int p = 0; p < 4; ++p) {
            int f  = t + 256 * p;
            int lr = f >> 5, c4 = f & 31;
            int gr = R0 + (lr >> 4) * 64 + m * 16 + (lr & 15);
            float4 o = *(const float4*)&Cs[lr * 132 + c4 * 4];
            *(float4*)(neg + (size_t)gr * Q + C0 + c4 * 4) = o;
        }
    }
}

// --- K3: reduce 1024 partial sums per row + pos -> loss_b -----------------
__global__ __launch_bounds__(256) void k_reduce_lse(const float* __restrict__ psum,
                                                    const float* __restrict__ ws_pos,
                                                    float* __restrict__ loss_b) {
    int r = blockIdx.x;
    const float4* pr = (const float4*)(psum + (size_t)r * NPART);
    float4 v = pr[threadIdx.x];        // 256 threads x float4 = 1024 slots
    float s = v.x + v.y + v.z + v.w;
    s = wave_reduce_sum(s);
    __shared__ float sw[4];
    int w = threadIdx.x >> 6, lane = threadIdx.x & 63;
    if (lane == 0) sw[w] = s;
    __syncthreads();
    if (threadIdx.x == 0) {
        float S = sw[0] + sw[1] + sw[2] + sw[3];
        float pos = ws_pos[r];
        S += __expf(pos - 5.0f);
        loss_b[r] = (logf(S) + 5.0f) - pos;   // lse - pos
    }
}

// --- K4: mean of loss_b -> out[0] -----------------------------------------
__global__ void k_loss_mean(const float* __restrict__ loss_b, float* __restrict__ out) {
    float s = 0.0f;
    for (int i = threadIdx.x; i < B; i += 256) s += loss_b[i];
    s = wave_reduce_sum(s);
    __shared__ float sw[4];
    int w = threadIdx.x >> 6, lane = threadIdx.x & 63;
    if (lane == 0) sw[w] = s;
    __syncthreads();
    if (threadIdx.x == 0) out[0] = (sw[0] + sw[1] + sw[2] + sw[3]) / (float)B;
}

extern "C" void kernel_launch(void* const* d_in, const int* in_sizes, int n_in,
                              void* d_out, int out_size, void* d_ws, size_t ws_size,
                              hipStream_t stream) {
    const float* g1    = (const float*)d_in[0];
    const float* g2    = (const float*)d_in[1];
    const float* queue = (const float*)d_in[2];
    float* out = (float*)d_out;

    float* out_pos = out + 1;          // pos_sim [B]
    float* neg     = out + 1 + B;      // neg_sim [B][Q]

    // ws layout: qnb bf16[B*D] | qinv f32[Q] | psum f32[B*NPART]
    //            | ws_pos f32[B] | loss_b f32[B]
    unsigned short* qnb = (unsigned short*)d_ws;
    float* qinv   = (float*)(qnb + (size_t)B * D);
    float* psum   = qinv + Q;
    float* ws_pos = psum + (size_t)B * NPART;
    float* loss_b = ws_pos + B;

    k_prep<<<Q / 8 + B / 2, 256, 0, stream>>>(g1, g2, queue, qnb, qinv, out_pos, ws_pos);
    k_gemm_mfma<<<(Q / 128) * (B / 128), 256, 0, stream>>>(qnb, queue, qinv, neg, psum);
    k_reduce_lse<<<B, 256, 0, stream>>>(psum, ws_pos, loss_b);
    k_loss_mean<<<1, 256, 0, stream>>>(loss_b, out);
}

// Round 10
// 93.107 us; speedup vs baseline: 1.6024x; 1.1580x over previous
//
#include <hip/hip_runtime.h>
#include <math.h>

constexpr int B = 1024;
constexpr int D = 128;
constexpr int Q = 65536;
constexpr int NPART = 1024;      // 256 N-tiles x 4 wave-cols
#define TEMP_INV 5.0f
#define EPS 1e-12f

typedef __bf16 bf16x8 __attribute__((ext_vector_type(8)));
typedef float  f32x4  __attribute__((ext_vector_type(4)));

__device__ __forceinline__ float wave_reduce_sum(float v) {
    #pragma unroll
    for (int off = 32; off > 0; off >>= 1) v += __shfl_xor(v, off);
    return v;
}

__device__ __forceinline__ unsigned short f2bf(float x) {
    unsigned int u = __float_as_uint(x);
    unsigned int r = (u + 0x7FFFu + ((u >> 16) & 1u)) >> 16;   // RNE
    return (unsigned short)r;
}

// --- K1: fused preprocessing (R6-verbatim) --------------------------------
// blocks [0, 8192):  l2-normalize 8 queue rows -> bf16 qb
// blocks [8192, 8704): normalize 2 g1/g2 rows -> qnb bf16, pos_sim
__global__ __launch_bounds__(256) void k_prep(const float* __restrict__ g1,
                                              const float* __restrict__ g2,
                                              const float* __restrict__ queue,
                                              unsigned short* __restrict__ qnb,
                                              unsigned short* __restrict__ qb,
                                              float* __restrict__ out_pos,
                                              float* __restrict__ ws_pos) {
    if (blockIdx.x < Q / 8) {
        int half = threadIdx.x >> 5;        // 0..7
        int l    = threadIdx.x & 31;
        int row  = blockIdx.x * 8 + half;
        const f32x4* src = (const f32x4*)(queue + (size_t)row * D);
        f32x4 v = __builtin_nontemporal_load(&src[l]);
        float ss = v.x * v.x + v.y * v.y + v.z * v.z + v.w * v.w;
        #pragma unroll
        for (int off = 16; off > 0; off >>= 1) ss += __shfl_xor(ss, off);
        float inv = 1.0f / fmaxf(sqrtf(ss), EPS);
        uint2 o;
        o.x = (unsigned int)f2bf(v.x * inv) | ((unsigned int)f2bf(v.y * inv) << 16);
        o.y = (unsigned int)f2bf(v.z * inv) | ((unsigned int)f2bf(v.w * inv) << 16);
        ((uint2*)(qb + (size_t)row * D))[l] = o;
    } else {
        int idx = blockIdx.x - Q / 8;
        int w2 = threadIdx.x >> 7;          // row within block (0..1)
        int tt = threadIdx.x & 127;         // 0..127 feature dim
        int b  = idx * 2 + w2;
        int w  = tt >> 6, lane = tt & 63;
        float x = g1[b * D + tt];
        float y = g2[b * D + tt];
        __shared__ float sx[2][2], sy[2][2], sp[2][2];
        float xs = wave_reduce_sum(x * x);
        float ys = wave_reduce_sum(y * y);
        if (lane == 0) { sx[w2][w] = xs; sy[w2][w] = ys; }
        __syncthreads();
        float ix = 1.0f / fmaxf(sqrtf(sx[w2][0] + sx[w2][1]), EPS);
        float iy = 1.0f / fmaxf(sqrtf(sy[w2][0] + sy[w2][1]), EPS);
        float qv = x * ix;
        float kv = y * iy;
        qnb[b * D + tt] = f2bf(qv);
        float p = wave_reduce_sum(qv * kv);
        if (lane == 0) sp[w2][w] = p;
        __syncthreads();
        if (tt == 0) {
            float pos = (sp[w2][0] + sp[w2][1]) * TEMP_INV;
            out_pos[b] = pos;
            ws_pos[b]  = pos;
        }
    }
}

// --- K2: MFMA GEMM + fused fixed-ref partial sumexp -----------------------
// 256x256 tile, 1024 threads, 4x4 waves (each wave 64x64 = R6's shape).
// Halves staged tile reads vs 128x128 (1024 blocks x 128KB = 128MB).
// 1-D grid, by-fastest: 4 consecutive blocks share one qb tile.
__global__ __launch_bounds__(1024) void k_gemm_mfma(const unsigned short* __restrict__ qnb,
                                                    const unsigned short* __restrict__ qb,
                                                    float* __restrict__ neg,
                                                    float* __restrict__ psum) {
    __shared__ unsigned short SM[2][256][72];   // As=SM[0], Bs=SM[1]; 73.7KB
    const int t  = threadIdx.x;
    const int blk = blockIdx.x;
    const int bx = blk >> 2;       // 0..255 over Q (slow)
    const int by = blk & 3;        // 0..3   over B (fast -> qb-tile reuse)
    const int R0 = by * 256, C0 = bx * 256;
    const int wid = t >> 6, lane = t & 63;
    const int wr = wid >> 2, wc = wid & 3;    // 4x4 wave grid
    const int lg = lane >> 4, lc = lane & 15;

    f32x4 acc[4][4];
    #pragma unroll
    for (int m = 0; m < 4; ++m)
        #pragma unroll
        for (int n = 0; n < 4; ++n)
            #pragma unroll
            for (int r = 0; r < 4; ++r) acc[m][n][r] = 0.0f;

    #pragma unroll
    for (int s = 0; s < 2; ++s) {
        if (s) __syncthreads();
        const int ks = s * 64;
        #pragma unroll
        for (int p = 0; p < 2; ++p) {
            int c   = t + 1024 * p;
            int row = c >> 3;          // 0..255
            int off = (c & 7) * 8;     // bf16 col, 0..56
            uint4 va = *(const uint4*)(qnb + (size_t)(R0 + row) * D + ks + off);
            uint4 vb = *(const uint4*)(qb  + (size_t)(C0 + row) * D + ks + off);
            *(uint4*)&SM[0][row][off] = va;
            *(uint4*)&SM[1][row][off] = vb;
        }
        __syncthreads();
        #pragma unroll
        for (int kk = 0; kk < 64; kk += 32) {
            int ko = kk + lg * 8;
            bf16x8 a[4], b[4];
            #pragma unroll
            for (int m = 0; m < 4; ++m)
                a[m] = *(const bf16x8*)&SM[0][wr * 64 + m * 16 + lc][ko];
            #pragma unroll
            for (int n = 0; n < 4; ++n)
                b[n] = *(const bf16x8*)&SM[1][wc * 64 + n * 16 + lc][ko];
            #pragma unroll
            for (int m = 0; m < 4; ++m)
                #pragma unroll
                for (int n = 0; n < 4; ++n)
                    acc[m][n] = __builtin_amdgcn_mfma_f32_16x16x32_bf16(a[m], b[n], acc[m][n], 0, 0, 0);
        }
    }

    // ---- epilogue: 4 slices of 64 rows (frag m from every wr -> all 16
    //      waves active). LDS transpose through Cs[64][260] (aliases SM),
    //      fused fixed-ref sumexp (M=5), 1KB/wave coalesced f4 stores.
    float* Cs = (float*)&SM[0][0][0];  // 64*260*4 = 66.6KB <= 73.7KB
    const int slot = bx * 4 + wc;
    #pragma unroll
    for (int m = 0; m < 4; ++m) {
        __syncthreads();               // prev slice reads (or MFMA LDS reads) done
        #pragma unroll
        for (int reg = 0; reg < 4; ++reg) {
            float v0 = acc[m][0][reg] * TEMP_INV;
            float v1 = acc[m][1][reg] * TEMP_INV;
            float v2 = acc[m][2][reg] * TEMP_INV;
            float v3 = acc[m][3][reg] * TEMP_INV;
            int cr = (wr * 16 + lg * 4 + reg) * 260 + wc * 64 + lc;
            Cs[cr +  0] = v0;
            Cs[cr + 16] = v1;
            Cs[cr + 32] = v2;
            Cs[cr + 48] = v3;
            float e = __expf(v0 - 5.0f) + __expf(v1 - 5.0f) +
                      __expf(v2 - 5.0f) + __expf(v3 - 5.0f);
            #pragma unroll
            for (int off = 1; off < 16; off <<= 1) e += __shfl_xor(e, off);
            if (lc == 0) {
                int gr = R0 + wr * 64 + m * 16 + lg * 4 + reg;
                psum[(size_t)gr * NPART + slot] = e;
            }
        }
        __syncthreads();
        #pragma unroll
        for (int p = 0; p < 4; ++p) {
            int f  = t + 1024 * p;
            int lr = f >> 6, c4 = f & 63;
            int gr = R0 + (lr >> 4) * 64 + m * 16 + (lr & 15);
            float4 o = *(const float4*)&Cs[lr * 260 + c4 * 4];
            *(float4*)(neg + (size_t)gr * Q + C0 + c4 * 4) = o;
        }
    }
}

// --- K3: reduce 1024 partial sums per row + pos -> loss_b -----------------
__global__ __launch_bounds__(256) void k_reduce_lse(const float* __restrict__ psum,
                                                    const float* __restrict__ ws_pos,
                                                    float* __restrict__ loss_b) {
    int r = blockIdx.x;
    const float4* pr = (const float4*)(psum + (size_t)r * NPART);
    float4 v = pr[threadIdx.x];        // 256 threads x float4 = 1024 slots
    float s = v.x + v.y + v.z + v.w;
    s = wave_reduce_sum(s);
    __shared__ float sw[4];
    int w = threadIdx.x >> 6, lane = threadIdx.x & 63;
    if (lane == 0) sw[w] = s;
    __syncthreads();
    if (threadIdx.x == 0) {
        float S = sw[0] + sw[1] + sw[2] + sw[3];
        float pos = ws_pos[r];
        S += __expf(pos - 5.0f);
        loss_b[r] = (logf(S) + 5.0f) - pos;   // lse - pos
    }
}

// --- K4: mean of loss_b -> out[0] -----------------------------------------
__global__ void k_loss_mean(const float* __restrict__ loss_b, float* __restrict__ out) {
    float s = 0.0f;
    for (int i = threadIdx.x; i < B; i += 256) s += loss_b[i];
    s = wave_reduce_sum(s);
    __shared__ float sw[4];
    int w = threadIdx.x >> 6, lane = threadIdx.x & 63;
    if (lane == 0) sw[w] = s;
    __syncthreads();
    if (threadIdx.x == 0) out[0] = (sw[0] + sw[1] + sw[2] + sw[3]) / (float)B;
}

extern "C" void kernel_launch(void* const* d_in, const int* in_sizes, int n_in,
                              void* d_out, int out_size, void* d_ws, size_t ws_size,
                              hipStream_t stream) {
    const float* g1    = (const float*)d_in[0];
    const float* g2    = (const float*)d_in[1];
    const float* queue = (const float*)d_in[2];
    float* out = (float*)d_out;

    float* out_pos = out + 1;          // pos_sim [B]
    float* neg     = out + 1 + B;      // neg_sim [B][Q]

    // ws layout: qnb bf16[B*D] | qb bf16[Q*D] | psum f32[B*NPART]
    //            | ws_pos f32[B] | loss_b f32[B]
    unsigned short* qnb = (unsigned short*)d_ws;
    unsigned short* qb  = qnb + (size_t)B * D;
    float* psum   = (float*)(qb + (size_t)Q * D);
    float* ws_pos = psum + (size_t)B * NPART;
    float* loss_b = ws_pos + B;

    k_prep<<<Q / 8 + B / 2, 256, 0, stream>>>(g1, g2, queue, qnb, qb, out_pos, ws_pos);
    k_gemm_mfma<<<(Q / 256) * (B / 256), 1024, 0, stream>>>(qnb, qb, neg, psum);
    k_reduce_lse<<<B, 256, 0, stream>>>(psum, ws_pos, loss_b);
    k_loss_mean<<<1, 256, 0, stream>>>(loss_b, out);
}

// Round 11
// 92.094 us; speedup vs baseline: 1.6201x; 1.0110x over previous
//
#include <hip/hip_runtime.h>
#include <math.h>

constexpr int B = 1024;
constexpr int D = 128;
constexpr int Q = 65536;
constexpr int NPART = 1024;      // 256 N-tiles x 4 wave-cols
#define TEMP_INV 5.0f
#define EPS 1e-12f

typedef __bf16 bf16x8 __attribute__((ext_vector_type(8)));
typedef float  f32x4  __attribute__((ext_vector_type(4)));

__device__ __forceinline__ float wave_reduce_sum(float v) {
    #pragma unroll
    for (int off = 32; off > 0; off >>= 1) v += __shfl_xor(v, off);
    return v;
}

__device__ __forceinline__ unsigned short f2bf(float x) {
    unsigned int u = __float_as_uint(x);
    unsigned int r = (u + 0x7FFFu + ((u >> 16) & 1u)) >> 16;   // RNE
    return (unsigned short)r;
}

// --- K1: fused preprocessing (R6-verbatim) --------------------------------
// blocks [0, 8192):  l2-normalize 8 queue rows -> bf16 qb
// blocks [8192, 8704): normalize 2 g1/g2 rows -> qnb bf16, pos_sim
__global__ __launch_bounds__(256) void k_prep(const float* __restrict__ g1,
                                              const float* __restrict__ g2,
                                              const float* __restrict__ queue,
                                              unsigned short* __restrict__ qnb,
                                              unsigned short* __restrict__ qb,
                                              float* __restrict__ out_pos,
                                              float* __restrict__ ws_pos) {
    if (blockIdx.x < Q / 8) {
        int half = threadIdx.x >> 5;        // 0..7
        int l    = threadIdx.x & 31;
        int row  = blockIdx.x * 8 + half;
        const f32x4* src = (const f32x4*)(queue + (size_t)row * D);
        f32x4 v = __builtin_nontemporal_load(&src[l]);
        float ss = v.x * v.x + v.y * v.y + v.z * v.z + v.w * v.w;
        #pragma unroll
        for (int off = 16; off > 0; off >>= 1) ss += __shfl_xor(ss, off);
        float inv = 1.0f / fmaxf(sqrtf(ss), EPS);
        uint2 o;
        o.x = (unsigned int)f2bf(v.x * inv) | ((unsigned int)f2bf(v.y * inv) << 16);
        o.y = (unsigned int)f2bf(v.z * inv) | ((unsigned int)f2bf(v.w * inv) << 16);
        ((uint2*)(qb + (size_t)row * D))[l] = o;
    } else {
        int idx = blockIdx.x - Q / 8;
        int w2 = threadIdx.x >> 7;          // row within block (0..1)
        int tt = threadIdx.x & 127;         // 0..127 feature dim
        int b  = idx * 2 + w2;
        int w  = tt >> 6, lane = tt & 63;
        float x = g1[b * D + tt];
        float y = g2[b * D + tt];
        __shared__ float sx[2][2], sy[2][2], sp[2][2];
        float xs = wave_reduce_sum(x * x);
        float ys = wave_reduce_sum(y * y);
        if (lane == 0) { sx[w2][w] = xs; sy[w2][w] = ys; }
        __syncthreads();
        float ix = 1.0f / fmaxf(sqrtf(sx[w2][0] + sx[w2][1]), EPS);
        float iy = 1.0f / fmaxf(sqrtf(sy[w2][0] + sy[w2][1]), EPS);
        float qv = x * ix;
        float kv = y * iy;
        qnb[b * D + tt] = f2bf(qv);
        float p = wave_reduce_sum(qv * kv);
        if (lane == 0) sp[w2][w] = p;
        __syncthreads();
        if (tt == 0) {
            float pos = (sp[w2][0] + sp[w2][1]) * TEMP_INV;
            out_pos[b] = pos;
            ws_pos[b]  = pos;
        }
    }
}

// --- K2: MFMA GEMM + fused fixed-ref partial sumexp -----------------------
// 256x256 tile, 1024 threads, 4x4 waves (each wave 64x64 output).
// SWAPPED-OPERAND MFMA: acc[n][m] = mfma(b[n], a[m]) -> output row=j, col=b;
// each lane's 4 regs are 4 consecutive j -> direct float4 stores from regs,
// no LDS transpose, no post-K barriers.
// 1-D grid, by-fastest: 4 consecutive blocks share one qb tile.
__global__ __launch_bounds__(1024) void k_gemm_mfma(const unsigned short* __restrict__ qnb,
                                                    const unsigned short* __restrict__ qb,
                                                    float* __restrict__ neg,
                                                    float* __restrict__ psum) {
    __shared__ unsigned short SM[2][256][72];   // As=SM[0], Bs=SM[1]; 73.7KB
    const int t  = threadIdx.x;
    const int blk = blockIdx.x;
    const int bx = blk >> 2;       // 0..255 over Q (slow)
    const int by = blk & 3;        // 0..3   over B (fast -> qb-tile reuse)
    const int R0 = by * 256, C0 = bx * 256;
    const int wid = t >> 6, lane = t & 63;
    const int wr = wid >> 2, wc = wid & 3;    // 4x4 wave grid
    const int lg = lane >> 4, lc = lane & 15;

    f32x4 acc[4][4];               // [n][m] (transposed output)
    #pragma unroll
    for (int n = 0; n < 4; ++n)
        #pragma unroll
        for (int m = 0; m < 4; ++m)
            #pragma unroll
            for (int r = 0; r < 4; ++r) acc[n][m][r] = 0.0f;

    #pragma unroll
    for (int s = 0; s < 2; ++s) {
        if (s) __syncthreads();
        const int ks = s * 64;
        #pragma unroll
        for (int p = 0; p < 2; ++p) {
            int c   = t + 1024 * p;
            int row = c >> 3;          // 0..255
            int off = (c & 7) * 8;     // bf16 col, 0..56
            uint4 va = *(const uint4*)(qnb + (size_t)(R0 + row) * D + ks + off);
            uint4 vb = *(const uint4*)(qb  + (size_t)(C0 + row) * D + ks + off);
            *(uint4*)&SM[0][row][off] = va;
            *(uint4*)&SM[1][row][off] = vb;
        }
        __syncthreads();
        #pragma unroll
        for (int kk = 0; kk < 64; kk += 32) {
            int ko = kk + lg * 8;
            bf16x8 a[4], b[4];
            #pragma unroll
            for (int m = 0; m < 4; ++m)
                a[m] = *(const bf16x8*)&SM[0][wr * 64 + m * 16 + lc][ko];
            #pragma unroll
            for (int n = 0; n < 4; ++n)
                b[n] = *(const bf16x8*)&SM[1][wc * 64 + n * 16 + lc][ko];
            #pragma unroll
            for (int n = 0; n < 4; ++n)
                #pragma unroll
                for (int m = 0; m < 4; ++m)
                    acc[n][m] = __builtin_amdgcn_mfma_f32_16x16x32_bf16(b[n], a[m], acc[n][m], 0, 0, 0);
        }
    }

    // ---- epilogue: direct register->global float4 stores + fused fixed-ref
    //      sumexp (logits in [-5,5] -> M=5). No barriers, no LDS.
    //      Lane (lg,lc), frag (n,m): row b = R0+wr*64+m*16+lc,
    //      cols j = C0+wc*64+n*16+lg*4 .. +3 (4 consecutive -> float4).
    const int slot = bx * 4 + wc;
    #pragma unroll
    for (int m = 0; m < 4; ++m) {
        const size_t rowBase = (size_t)(R0 + wr * 64 + m * 16 + lc) * Q + C0 + wc * 64;
        float e = 0.0f;
        #pragma unroll
        for (int n = 0; n < 4; ++n) {
            float v0 = acc[n][m][0] * TEMP_INV;
            float v1 = acc[n][m][1] * TEMP_INV;
            float v2 = acc[n][m][2] * TEMP_INV;
            float v3 = acc[n][m][3] * TEMP_INV;
            float4 o = make_float4(v0, v1, v2, v3);
            *(float4*)(neg + rowBase + n * 16 + lg * 4) = o;
            e += __expf(v0 - 5.0f) + __expf(v1 - 5.0f) +
                 __expf(v2 - 5.0f) + __expf(v3 - 5.0f);
        }
        // reduce over the 4 lg-groups holding this row's 64 j values
        e += __shfl_xor(e, 16);
        e += __shfl_xor(e, 32);
        if (lg == 0) {
            int gr = R0 + wr * 64 + m * 16 + lc;
            psum[(size_t)gr * NPART + slot] = e;
        }
    }
}

// --- K3: reduce 1024 partial sums per row + pos -> loss_b -----------------
__global__ __launch_bounds__(256) void k_reduce_lse(const float* __restrict__ psum,
                                                    const float* __restrict__ ws_pos,
                                                    float* __restrict__ loss_b) {
    int r = blockIdx.x;
    const float4* pr = (const float4*)(psum + (size_t)r * NPART);
    float4 v = pr[threadIdx.x];        // 256 threads x float4 = 1024 slots
    float s = v.x + v.y + v.z + v.w;
    s = wave_reduce_sum(s);
    __shared__ float sw[4];
    int w = threadIdx.x >> 6, lane = threadIdx.x & 63;
    if (lane == 0) sw[w] = s;
    __syncthreads();
    if (threadIdx.x == 0) {
        float S = sw[0] + sw[1] + sw[2] + sw[3];
        float pos = ws_pos[r];
        S += __expf(pos - 5.0f);
        loss_b[r] = (logf(S) + 5.0f) - pos;   // lse - pos
    }
}

// --- K4: mean of loss_b -> out[0] -----------------------------------------
__global__ void k_loss_mean(const float* __restrict__ loss_b, float* __restrict__ out) {
    float s = 0.0f;
    for (int i = threadIdx.x; i < B; i += 256) s += loss_b[i];
    s = wave_reduce_sum(s);
    __shared__ float sw[4];
    int w = threadIdx.x >> 6, lane = threadIdx.x & 63;
    if (lane == 0) sw[w] = s;
    __syncthreads();
    if (threadIdx.x == 0) out[0] = (sw[0] + sw[1] + sw[2] + sw[3]) / (float)B;
}

extern "C" void kernel_launch(void* const* d_in, const int* in_sizes, int n_in,
                              void* d_out, int out_size, void* d_ws, size_t ws_size,
                              hipStream_t stream) {
    const float* g1    = (const float*)d_in[0];
    const float* g2    = (const float*)d_in[1];
    const float* queue = (const float*)d_in[2];
    float* out = (float*)d_out;

    float* out_pos = out + 1;          // pos_sim [B]
    float* neg     = out + 1 + B;      // neg_sim [B][Q]

    // ws layout: qnb bf16[B*D] | qb bf16[Q*D] | psum f32[B*NPART]
    //            | ws_pos f32[B] | loss_b f32[B]
    unsigned short* qnb = (unsigned short*)d_ws;
    unsigned short* qb  = qnb + (size_t)B * D;
    float* psum   = (float*)(qb + (size_t)Q * D);
    float* ws_pos = psum + (size_t)B * NPART;
    float* loss_b = ws_pos + B;

    k_prep<<<Q / 8 + B / 2, 256, 0, stream>>>(g1, g2, queue, qnb, qb, out_pos, ws_pos);
    k_gemm_mfma<<<(Q / 256) * (B / 256), 1024, 0, stream>>>(qnb, qb, neg, psum);
    k_reduce_lse<<<B, 256, 0, stream>>>(psum, ws_pos, loss_b);
    k_loss_mean<<<1, 256, 0, stream>>>(loss_b, out);
}